// Round 1
// baseline (141.208 us; speedup 1.0000x reference)
//
#include <hip/hip_runtime.h>
#include <math.h>

#define W_DIM 256
#define H_DIM 256
#define ROWS_PER_BLOCK 4

__device__ __forceinline__ void load_row(const float* __restrict__ rowp, int j,
                                         float4& v, float& l, float& r) {
    v = *reinterpret_cast<const float4*>(rowp + j);
    l = (j > 0) ? rowp[j - 1] : INFINITY;
    r = (j + 4 < W_DIM) ? rowp[j + 4] : INFINITY;
}

__global__ __launch_bounds__(256) void MinValues_kernel(const float* __restrict__ x,
                                                        float* __restrict__ out) {
    const int tid = threadIdx.x;                    // 0..63 -> 4 outputs each along W
    const int ty  = threadIdx.y;                    // 0..3  -> row within block tile
    const int i   = blockIdx.x * ROWS_PER_BLOCK + ty; // output row
    const int img = blockIdx.y;                     // n*C + c
    const int j   = tid * 4;                        // output col base

    const float* base = x + (size_t)img * (H_DIM * W_DIM);

    float4 t, m, b;
    float tl, tr, ml, mr, bl, br;

    // top row (i-1)
    if (i > 0) {
        load_row(base + (size_t)(i - 1) * W_DIM, j, t, tl, tr);
    } else {
        t = make_float4(INFINITY, INFINITY, INFINITY, INFINITY);
        tl = INFINITY; tr = INFINITY;
    }
    // middle row (i)
    load_row(base + (size_t)i * W_DIM, j, m, ml, mr);
    // bottom row (i+1)
    if (i + 1 < H_DIM) {
        load_row(base + (size_t)(i + 1) * W_DIM, j, b, bl, br);
    } else {
        b = make_float4(INFINITY, INFINITY, INFINITY, INFINITY);
        bl = INFINITY; br = INFINITY;
    }

    // horizontal min of 3 (rows above/below: all 3 columns participate)
    float4 th, bh, mh;
    th.x = fminf(fminf(tl,  t.x), t.y);
    th.y = fminf(fminf(t.x, t.y), t.z);
    th.z = fminf(fminf(t.y, t.z), t.w);
    th.w = fminf(fminf(t.z, t.w), tr);

    bh.x = fminf(fminf(bl,  b.x), b.y);
    bh.y = fminf(fminf(b.x, b.y), b.z);
    bh.z = fminf(fminf(b.y, b.z), b.w);
    bh.w = fminf(fminf(b.z, b.w), br);

    // middle row: skip the center element
    mh.x = fminf(ml,  m.y);
    mh.y = fminf(m.x, m.z);
    mh.z = fminf(m.y, m.w);
    mh.w = fminf(m.z, mr);

    float4 o;
    o.x = fminf(fminf(th.x, mh.x), bh.x);
    o.y = fminf(fminf(th.y, mh.y), bh.y);
    o.z = fminf(fminf(th.z, mh.z), bh.z);
    o.w = fminf(fminf(th.w, mh.w), bh.w);

    float* op = out + (size_t)img * (H_DIM * W_DIM) + (size_t)i * W_DIM + j;
    *reinterpret_cast<float4*>(op) = o;
}

extern "C" void kernel_launch(void* const* d_in, const int* in_sizes, int n_in,
                              void* d_out, int out_size, void* d_ws, size_t ws_size,
                              hipStream_t stream) {
    const float* x = (const float*)d_in[0];
    float* out = (float*)d_out;

    const int total  = in_sizes[0];                 // N*C*H*W
    const int n_imgs = total / (H_DIM * W_DIM);     // N*C = 1024

    dim3 block(64, ROWS_PER_BLOCK);                 // 256 threads
    dim3 grid(H_DIM / ROWS_PER_BLOCK, n_imgs);      // 64 x 1024 blocks

    MinValues_kernel<<<grid, block, 0, stream>>>(x, out);
}

// Round 2
// 135.704 us; speedup vs baseline: 1.0406x; 1.0406x over previous
//
#include <hip/hip_runtime.h>
#include <math.h>

#define W_DIM 256
#define H_DIM 256
#define VROWS 8                 // output rows per thread
#define TY    4                 // waves per block
#define TILE_ROWS (VROWS * TY)  // 32 output rows per block
#define N_TILES (H_DIM / TILE_ROWS)  // 8 tiles per image

// Load global row r (or +INF if out of range), compute per-lane:
//   hs = min(left, right)          (horizontal min skipping center)
//   h3 = min(left, center, right)  (horizontal min of 3)
// Horizontal halo comes from neighbor lanes via shuffle — no extra loads.
__device__ __forceinline__ void prep_row(const float* __restrict__ base, int r,
                                         int lane, float4& h3, float4& hs) {
    float4 v;
    if (r >= 0 && r < H_DIM) {
        v = *reinterpret_cast<const float4*>(base + (size_t)r * W_DIM + lane * 4);
    } else {
        v = make_float4(INFINITY, INFINITY, INFINITY, INFINITY);
    }
    float lf = __shfl_up(v.w, 1);    // lane i-1's last element
    if (lane == 0) lf = INFINITY;
    float rf = __shfl_down(v.x, 1);  // lane i+1's first element
    if (lane == 63) rf = INFINITY;

    // shifted-left  = [lf,  v.x, v.y, v.z]
    // shifted-right = [v.y, v.z, v.w, rf ]
    hs.x = fminf(lf,  v.y);
    hs.y = fminf(v.x, v.z);
    hs.z = fminf(v.y, v.w);
    hs.w = fminf(v.z, rf);
    h3.x = fminf(hs.x, v.x);
    h3.y = fminf(hs.y, v.y);
    h3.z = fminf(hs.z, v.z);
    h3.w = fminf(hs.w, v.w);
}

__global__ __launch_bounds__(256) void MinValues_kernel(const float* __restrict__ x,
                                                        float* __restrict__ out,
                                                        int nwg) {
    // Bijective XCD swizzle: consecutive work-ids land on the same XCD so
    // vertically adjacent tiles share L2 for halo rows. nwg % 8 == 0.
    const int bid = blockIdx.x;
    const int wg  = (bid & 7) * (nwg >> 3) + (bid >> 3);

    const int img  = wg >> 3;            // wg / N_TILES
    const int tile = wg & (N_TILES - 1);

    const int lane = threadIdx.x;        // 0..63 -> 4 floats each along W
    const int ty   = threadIdx.y;        // 0..3
    const int i0   = tile * TILE_ROWS + ty * VROWS;  // first output row

    const float* base = x + (size_t)img * (H_DIM * W_DIM);
    float* obase = out + (size_t)img * (H_DIM * W_DIM) + (size_t)i0 * W_DIM + lane * 4;

    float4 h3_t, hs_t;   // row i-1
    float4 h3_m, hs_m;   // row i
    prep_row(base, i0 - 1, lane, h3_t, hs_t);
    prep_row(base, i0,     lane, h3_m, hs_m);

#pragma unroll
    for (int k = 0; k < VROWS; ++k) {
        float4 h3_b, hs_b;               // row i+k+1
        prep_row(base, i0 + k + 1, lane, h3_b, hs_b);

        float4 o;
        o.x = fminf(fminf(h3_t.x, hs_m.x), h3_b.x);
        o.y = fminf(fminf(h3_t.y, hs_m.y), h3_b.y);
        o.z = fminf(fminf(h3_t.z, hs_m.z), h3_b.z);
        o.w = fminf(fminf(h3_t.w, hs_m.w), h3_b.w);

        *reinterpret_cast<float4*>(obase + (size_t)k * W_DIM) = o;

        h3_t = h3_m;
        h3_m = h3_b;
        hs_m = hs_b;
    }
}

extern "C" void kernel_launch(void* const* d_in, const int* in_sizes, int n_in,
                              void* d_out, int out_size, void* d_ws, size_t ws_size,
                              hipStream_t stream) {
    const float* x = (const float*)d_in[0];
    float* out = (float*)d_out;

    const int total  = in_sizes[0];                 // N*C*H*W
    const int n_imgs = total / (H_DIM * W_DIM);     // 1024
    const int nwg    = n_imgs * N_TILES;            // 8192

    dim3 block(64, TY);                             // 256 threads
    MinValues_kernel<<<dim3(nwg), block, 0, stream>>>(x, out, nwg);
}

// Round 3
// 100.567 us; speedup vs baseline: 1.4041x; 1.3494x over previous
//
#include <hip/hip_runtime.h>
#include <math.h>

#define W_DIM 256
#define H_DIM 256
#define VROWS 4                       // output rows per thread
#define TY    4                       // waves per block
#define TILE_ROWS (VROWS * TY)        // 16 output rows per block
#define N_TILES (H_DIM / TILE_ROWS)   // 16 tiles per image
#define NROWS (VROWS + 2)             // rows loaded per thread

__global__ __launch_bounds__(256) void MinValues_kernel(const float* __restrict__ x,
                                                        float* __restrict__ out,
                                                        int nwg) {
    // Bijective XCD swizzle (nwg % 8 == 0): consecutive blocks on one XCD
    // process consecutive tiles -> vertical halo rows reuse the XCD's L2.
    const int bid = blockIdx.x;
    const int wg  = (bid & 7) * (nwg >> 3) + (bid >> 3);

    const int img  = wg >> 4;              // wg / N_TILES
    const int tile = wg & (N_TILES - 1);

    const int lane = threadIdx.x;          // 0..63, 4 floats each along W
    const int ty   = threadIdx.y;          // 0..3
    const int i0   = tile * TILE_ROWS + ty * VROWS;

    const float* base = x + (size_t)img * (H_DIM * W_DIM) + lane * 4;

    // ---- Phase 1: issue ALL row loads back-to-back (max MLP, no branches) ----
    float4 v[NROWS];
    bool oob[NROWS];
#pragma unroll
    for (int r = 0; r < NROWS; ++r) {
        int row = i0 - 1 + r;
        oob[r] = (row < 0) | (row >= H_DIM);
        int rc = row < 0 ? 0 : (row > H_DIM - 1 ? H_DIM - 1 : row);  // clamped, always in-bounds
        v[r] = *reinterpret_cast<const float4*>(base + (size_t)rc * W_DIM);
    }

    // ---- Phase 2: per-row horizontal mins (halo via wave shuffle) ----
    float4 h3[NROWS], hs[NROWS];
#pragma unroll
    for (int r = 0; r < NROWS; ++r) {
        float4 vr = v[r];
        if (oob[r]) vr = make_float4(INFINITY, INFINITY, INFINITY, INFINITY);

        float lf = __shfl_up(vr.w, 1);     // lane i-1's last element
        if (lane == 0) lf = INFINITY;
        float rf = __shfl_down(vr.x, 1);   // lane i+1's first element
        if (lane == 63) rf = INFINITY;

        hs[r].x = fminf(lf,   vr.y);
        hs[r].y = fminf(vr.x, vr.z);
        hs[r].z = fminf(vr.y, vr.w);
        hs[r].w = fminf(vr.z, rf);
        h3[r].x = fminf(hs[r].x, vr.x);
        h3[r].y = fminf(hs[r].y, vr.y);
        h3[r].z = fminf(hs[r].z, vr.z);
        h3[r].w = fminf(hs[r].w, vr.w);
    }

    // ---- Phase 3: vertical combine + stores ----
    float* obase = out + (size_t)img * (H_DIM * W_DIM) + (size_t)i0 * W_DIM + lane * 4;
#pragma unroll
    for (int k = 0; k < VROWS; ++k) {
        float4 o;
        o.x = fminf(fminf(h3[k].x, hs[k + 1].x), h3[k + 2].x);
        o.y = fminf(fminf(h3[k].y, hs[k + 1].y), h3[k + 2].y);
        o.z = fminf(fminf(h3[k].z, hs[k + 1].z), h3[k + 2].z);
        o.w = fminf(fminf(h3[k].w, hs[k + 1].w), h3[k + 2].w);
        *reinterpret_cast<float4*>(obase + (size_t)k * W_DIM) = o;
    }
}

extern "C" void kernel_launch(void* const* d_in, const int* in_sizes, int n_in,
                              void* d_out, int out_size, void* d_ws, size_t ws_size,
                              hipStream_t stream) {
    const float* x = (const float*)d_in[0];
    float* out = (float*)d_out;

    const int total  = in_sizes[0];                 // N*C*H*W
    const int n_imgs = total / (H_DIM * W_DIM);     // 1024
    const int nwg    = n_imgs * N_TILES;            // 16384

    dim3 block(64, TY);                             // 256 threads
    MinValues_kernel<<<dim3(nwg), block, 0, stream>>>(x, out, nwg);
}

// Round 5
// 78.193 us; speedup vs baseline: 1.8059x; 1.2861x over previous
//
#include <hip/hip_runtime.h>
#include <math.h>

#define W_DIM 256
#define H_DIM 256
#define VROWS 8                       // output rows per thread
#define TY    4                       // waves per block
#define TILE_ROWS (VROWS * TY)        // 32 output rows per block
#define N_TILES (H_DIM / TILE_ROWS)   // 8 tiles per image
#define NROWS (VROWS + 2)             // rows loaded per thread

typedef float f32x4 __attribute__((ext_vector_type(4)));  // native vec for NT store

__device__ __forceinline__ void hmins(float4 vr, int lane, float4& h3, float4& hs) {
    float lf = __shfl_up(vr.w, 1);     // lane i-1's last element
    if (lane == 0) lf = INFINITY;
    float rf = __shfl_down(vr.x, 1);   // lane i+1's first element
    if (lane == 63) rf = INFINITY;

    hs.x = fminf(lf,   vr.y);
    hs.y = fminf(vr.x, vr.z);
    hs.z = fminf(vr.y, vr.w);
    hs.w = fminf(vr.z, rf);
    h3.x = fminf(hs.x, vr.x);
    h3.y = fminf(hs.y, vr.y);
    h3.z = fminf(hs.z, vr.z);
    h3.w = fminf(hs.w, vr.w);
}

__global__ __launch_bounds__(256) void MinValues_kernel(const float* __restrict__ x,
                                                        float* __restrict__ out,
                                                        int nwg) {
    // Bijective XCD swizzle (nwg % 8 == 0): consecutive work-ids share an XCD
    // so vertically adjacent tiles reuse halo rows in that XCD's L2.
    const int bid = blockIdx.x;
    const int wg  = (bid & 7) * (nwg >> 3) + (bid >> 3);

    const int img  = wg >> 3;              // wg / N_TILES
    const int tile = wg & (N_TILES - 1);

    const int lane = threadIdx.x;          // 0..63, 4 floats each along W
    const int ty   = threadIdx.y;          // 0..3
    const int i0   = tile * TILE_ROWS + ty * VROWS;

    const float* base = x + (size_t)img * (H_DIM * W_DIM) + lane * 4;

    // ---- Phase 1: issue ALL 10 row loads back-to-back (MLP=10) ----
    float4 v[NROWS];
    bool oob[NROWS];
#pragma unroll
    for (int r = 0; r < NROWS; ++r) {
        int row = i0 - 1 + r;
        oob[r] = (row < 0) | (row >= H_DIM);
        int rc = row < 0 ? 0 : (row > H_DIM - 1 ? H_DIM - 1 : row);
        v[r] = *reinterpret_cast<const float4*>(base + (size_t)rc * W_DIM);
    }

    // ---- Phase 2: rolling 3-row window (caps live h-registers) ----
    float* obase = out + (size_t)img * (H_DIM * W_DIM) + (size_t)i0 * W_DIM + lane * 4;

    const float4 VINF = make_float4(INFINITY, INFINITY, INFINITY, INFINITY);
    float4 h3_t, hs_t, h3_m, hs_m;
    hmins(oob[0] ? VINF : v[0], lane, h3_t, hs_t);
    hmins(oob[1] ? VINF : v[1], lane, h3_m, hs_m);

#pragma unroll
    for (int k = 0; k < VROWS; ++k) {
        float4 h3_b, hs_b;
        hmins(oob[k + 2] ? VINF : v[k + 2], lane, h3_b, hs_b);

        f32x4 o;
        o.x = fminf(fminf(h3_t.x, hs_m.x), h3_b.x);
        o.y = fminf(fminf(h3_t.y, hs_m.y), h3_b.y);
        o.z = fminf(fminf(h3_t.z, hs_m.z), h3_b.z);
        o.w = fminf(fminf(h3_t.w, hs_m.w), h3_b.w);

        // Output is never re-read: NT store keeps it from evicting input in L2/L3.
        __builtin_nontemporal_store(o, reinterpret_cast<f32x4*>(obase + (size_t)k * W_DIM));

        h3_t = h3_m;
        h3_m = h3_b;
        hs_m = hs_b;
    }
}

extern "C" void kernel_launch(void* const* d_in, const int* in_sizes, int n_in,
                              void* d_out, int out_size, void* d_ws, size_t ws_size,
                              hipStream_t stream) {
    const float* x = (const float*)d_in[0];
    float* out = (float*)d_out;

    const int total  = in_sizes[0];                 // N*C*H*W
    const int n_imgs = total / (H_DIM * W_DIM);     // 1024
    const int nwg    = n_imgs * N_TILES;            // 8192

    dim3 block(64, TY);                             // 256 threads
    MinValues_kernel<<<dim3(nwg), block, 0, stream>>>(x, out, nwg);
}